// Round 2
// baseline (342.286 us; speedup 1.0000x reference)
//
#include <hip/hip_runtime.h>
#include <cstddef>
#include <cstdint>

// ST-GCN block, MFMA + software-pipelined staging.
// Stage 1 (swapped operands): Yt[pos=64][os=192] tiles -> stored as Ys[os][pos] via
//   packed b64 LDS writes. pos = m*32 + v (v padded 25->32, pad rows zeroed once).
// Stage 2: Z[o=64][w] = sum_s Y_s[o][v] PA_s[v][w], K=32 (PA pads zero).
// This version:
//  - SINGLE X buffer (prefetch lives in regs across stage 1; residual reads moved
//    before B1 so Xb is dead after B1 and can be overwritten) -> LDS 46.6->37.4 KB,
//    4 blocks/CU instead of 3. Still 2 barriers/iteration.
//    Sync proof: [B0,B1): Xb read-only (bX frags + residual), Ys write-only.
//                [B1,B0'): Ys read-only (aY frags), Xb write-only (prefetch conv).
//  - Stage-2 wave owns (o-half, w-half) and computes BOTH m -> epilogue stores are
//    contiguous float2 (dense 128B segments) instead of stride-2 scalars.
//  - Residual read as 4x ds_read_b64 (2-way, free) instead of 16x ds_read_u16 (4-way).
//  - bf16 packing via known-good manual RNE (v_cvt_pk inline asm was the r1 failure).
#define N_  32
#define C_  64
#define T_  300
#define V_  25
#define M_  2
#define S_  3
#define O_  64
#define OS_ 192
#define TB  6             // t-values per block
#define NT_BLK (T_/TB)    // 50
#define CTVM (C_*T_*V_*M_)   // 960000
#define TVM  (T_*V_*M_)      // 15000
#define VM   (V_*M_)         // 50
#define XPITCH 72         // shorts; 144B rows
#define YPITCH 72

typedef short  short8  __attribute__((ext_vector_type(8)));
typedef float  float4_ __attribute__((ext_vector_type(4)));
typedef unsigned short ushort4_ __attribute__((ext_vector_type(4)));

__device__ __forceinline__ short f2bf(float f) {   // fp32 -> bf16 RNE
    uint32_t u = __float_as_uint(f);
    u += 0x7FFFu + ((u >> 16) & 1u);
    return (short)(u >> 16);
}
__device__ __forceinline__ unsigned pk2bf(float a, float b) {  // lo=a, hi=b
    const uint32_t ua = (uint32_t)(uint16_t)f2bf(a);
    const uint32_t ub = (uint32_t)(uint16_t)f2bf(b);
    return ua | (ub << 16);
}
__device__ __forceinline__ float bf2f(unsigned short u) {
    return __uint_as_float(((unsigned)u) << 16);
}

// prep: W -> bf16 [os][c]; PA -> bf16 transposed+padded [s][w32][v32]; BN fold.
__global__ void stgcn_prep(const float* __restrict__ Wc, const float* __restrict__ PA,
                           const float* __restrict__ g,  const float* __restrict__ b,
                           const float* __restrict__ mn, const float* __restrict__ vr,
                           short* __restrict__ Wb, short* __restrict__ PAb,
                           float* __restrict__ scl, float* __restrict__ sft)
{
    const int i = blockIdx.x * 256 + threadIdx.x;
    if (i < OS_ * C_) Wb[i] = f2bf(Wc[i]);
    const int r = i - OS_ * C_;
    if (r >= 0 && r < S_ * 32 * 32) {
        const int s = r >> 10, rem = r & 1023, wp = rem >> 5, vp = rem & 31;
        const float val = (wp < V_ && vp < V_) ? PA[s * V_ * V_ + vp * V_ + wp] : 0.0f;
        PAb[r] = f2bf(val);
    }
    const int q = r - S_ * 32 * 32;
    if (q >= 0 && q < O_) {
        const float sc = g[q] * rsqrtf(vr[q] + 1e-5f);
        scl[q] = sc;
        sft[q] = b[q] - mn[q] * sc;
    }
}

__global__ __launch_bounds__(256, 4)
void stgcn_main(const float* __restrict__ x, const float* __restrict__ cb,
                const short* __restrict__ Wb, const short* __restrict__ PAb,
                const float* __restrict__ sclg, const float* __restrict__ sftg,
                float* __restrict__ out)
{
    __shared__ short Xb[64 * XPITCH];      // 9.2 KB (single buffer)
    __shared__ short Ys[OS_ * YPITCH];     // 27.6 KB
    __shared__ float sclS[O_], sftS[O_];

    const int tid  = threadIdx.x;
    const int wv   = tid >> 6;
    const int lane = tid & 63;
    const int quad = lane >> 4;
    const int l15  = lane & 15;

    const int n  = blockIdx.x / NT_BLK;
    const int t0 = (blockIdx.x % NT_BLK) * TB;
    const size_t xbase = (size_t)n * CTVM;

    // zero v-pad rows (pos 25..31, 57..63), once
    for (int i = tid; i < 14 * XPITCH; i += 256) {
        const int pr = i / XPITCH, cc = i - pr * XPITCH;
        const int pos = (pr < 7) ? (25 + pr) : (50 + pr);
        Xb[pos * XPITCH + cc] = 0;
    }
    if (tid < O_) { sclS[tid] = sclg[tid]; sftS[tid] = sftg[tid]; }

    // ---- wave-constant fragments ----
    const int wbase = wv * 48;            // stage-1: this wave's 48 os rows
    short8 aW[3][2];                      // B-operand: B[k=c][n=os]
    #pragma unroll
    for (int mt = 0; mt < 3; ++mt)
        #pragma unroll
        for (int ks = 0; ks < 2; ++ks)
            aW[mt][ks] = *(const short8*)(Wb + (wbase + mt * 16 + l15) * C_ + ks * 32 + quad * 8);

    float cbw[3];                         // stage-1 bias: per COLUMN (os = l15-mapped)
    #pragma unroll
    for (int mt = 0; mt < 3; ++mt) cbw[mt] = cb[wbase + mt * 16 + l15];

    // stage-2: wave owns (o-half, w-half); computes BOTH m
    const int oh = wv >> 1, hh = wv & 1;
    const int wc = hh * 16 + l15;
    short8 bP[3];                         // B[k=v][n=w]
    #pragma unroll
    for (int s = 0; s < 3; ++s)
        bP[s] = *(const short8*)(PAb + s * 1024 + wc * 32 + quad * 8);

    // ---- prologue: stage t0 into Xb ----
    {
        const float* xt = x + xbase + (size_t)t0 * VM;
        #pragma unroll
        for (int k = 0; k < 4; ++k) {
            const int p = tid + k * 256;           // 800 (cpair, v) pairs
            if (p < 800) {
                const int v = p % 25, cp = p / 25;
                const float2 f0 = *(const float2*)(xt + (size_t)(2 * cp)     * TVM + v * 2);
                const float2 f1 = *(const float2*)(xt + (size_t)(2 * cp + 1) * TVM + v * 2);
                ((unsigned*)Xb)[v * 36 + cp]        = pk2bf(f0.x, f1.x);  // m=0
                ((unsigned*)Xb)[(32 + v) * 36 + cp] = pk2bf(f0.y, f1.y);  // m=1
            }
        }
    }

    for (int tt = 0; tt < TB; ++tt) {
        __syncthreads();   // B0: Xb staged; Ys free for rewrite

        // ---- issue prefetch loads for t+1 (converted after B1) ----
        float2 R0[4], R1[4];
        const bool pf = (tt + 1 < TB);
        if (pf) {
            const float* xt = x + xbase + (size_t)(t0 + tt + 1) * VM;
            #pragma unroll
            for (int k = 0; k < 4; ++k) {
                const int p = tid + k * 256;
                if (p < 800) {
                    const int v = p % 25, cp = p / 25;
                    R0[k] = *(const float2*)(xt + (size_t)(2 * cp)     * TVM + v * 2);
                    R1[k] = *(const float2*)(xt + (size_t)(2 * cp + 1) * TVM + v * 2);
                }
            }
        }

        // ---- stage-1 A frags + residual (ALL Xb reads happen before B1) ----
        short8 bX[4][2];                  // A[m=pos][k=c]
        #pragma unroll
        for (int nt = 0; nt < 4; ++nt)
            #pragma unroll
            for (int ks = 0; ks < 2; ++ks)
                bX[nt][ks] = *(const short8*)(Xb + (nt * 16 + l15) * XPITCH + ks * 32 + quad * 8);

        ushort4_ res[2][2];               // [otl][m] : residual bf16, 4 consecutive o
        #pragma unroll
        for (int otl = 0; otl < 2; ++otl)
            #pragma unroll
            for (int m = 0; m < 2; ++m)
                res[otl][m] = *(const ushort4_*)(Xb + (m * 32 + wc) * XPITCH + (oh * 2 + otl) * 16 + quad * 4);

        // ---- stage 1: D[pos][os] = X^T·W^T + cb ----
        #pragma unroll
        for (int mt = 0; mt < 3; ++mt) {
            #pragma unroll
            for (int nt = 0; nt < 4; ++nt) {
                float4_ acc = { cbw[mt], cbw[mt], cbw[mt], cbw[mt] };
                acc = __builtin_amdgcn_mfma_f32_16x16x32_bf16(bX[nt][0], aW[mt][0], acc, 0, 0, 0);
                acc = __builtin_amdgcn_mfma_f32_16x16x32_bf16(bX[nt][1], aW[mt][1], acc, 0, 0, 0);
                const int os = wbase + mt * 16 + l15;
                *(uint2*)(Ys + os * YPITCH + nt * 16 + quad * 4) =
                    make_uint2(pk2bf(acc[0], acc[1]), pk2bf(acc[2], acc[3]));
            }
        }
        __syncthreads();   // B1: Ys complete; Xb fully consumed by all waves

        // ---- stage 2: Z[o][w] = sum_s Y_s[o][v] PA_s[v][w], both m per wave ----
        float4_ z[2][2];
        #pragma unroll
        for (int otl = 0; otl < 2; ++otl)
            #pragma unroll
            for (int m = 0; m < 2; ++m) { z[otl][m][0]=0.f; z[otl][m][1]=0.f; z[otl][m][2]=0.f; z[otl][m][3]=0.f; }
        #pragma unroll
        for (int s = 0; s < 3; ++s) {
            #pragma unroll
            for (int otl = 0; otl < 2; ++otl) {
                #pragma unroll
                for (int m = 0; m < 2; ++m) {
                    const short8 aY = *(const short8*)(Ys + (s * 64 + (oh * 2 + otl) * 16 + l15) * YPITCH + m * 32 + quad * 8);
                    z[otl][m] = __builtin_amdgcn_mfma_f32_16x16x32_bf16(aY, bP[s], z[otl][m], 0, 0, 0);
                }
            }
        }

        // ---- convert prefetched regs into Xb (safe: all Xb reads drained at B1) ----
        if (pf) {
            #pragma unroll
            for (int k = 0; k < 4; ++k) {
                const int p = tid + k * 256;
                if (p < 800) {
                    const int v = p % 25, cp = p / 25;
                    ((unsigned*)Xb)[v * 36 + cp]        = pk2bf(R0[k].x, R1[k].x);
                    ((unsigned*)Xb)[(32 + v) * 36 + cp] = pk2bf(R0[k].y, R1[k].y);
                }
            }
        }

        // ---- epilogue: BN + relu + residual + relu; dense float2 stores ----
        const int t = t0 + tt;
        if (wc < V_) {
            #pragma unroll
            for (int otl = 0; otl < 2; ++otl) {
                #pragma unroll
                for (int r = 0; r < 4; ++r) {
                    const int o = (oh * 2 + otl) * 16 + quad * 4 + r;
                    const float sc = sclS[o], sh = sftS[o];
                    float q0 = fmaf(z[otl][0][r], sc, sh);
                    q0 = fmaxf(q0, 0.0f);
                    q0 = fmaxf(q0 + bf2f((unsigned short)res[otl][0][r]), 0.0f);
                    float q1 = fmaf(z[otl][1][r], sc, sh);
                    q1 = fmaxf(q1, 0.0f);
                    q1 = fmaxf(q1 + bf2f((unsigned short)res[otl][1][r]), 0.0f);
                    *(float2*)(out + xbase + (size_t)o * TVM + (size_t)t * VM + wc * 2) =
                        make_float2(q0, q1);
                }
            }
        }
    }
}

extern "C" void kernel_launch(void* const* d_in, const int* in_sizes, int n_in,
                              void* d_out, int out_size, void* d_ws, size_t ws_size,
                              hipStream_t stream)
{
    const float* x    = (const float*)d_in[0];  // (32,64,300,25,2)
    const float* PA   = (const float*)d_in[1];  // (3,25,25)
    const float* Wc   = (const float*)d_in[2];  // (192,64)
    const float* cb   = (const float*)d_in[3];  // (192,)
    const float* bn_g = (const float*)d_in[4];
    const float* bn_b = (const float*)d_in[5];
    const float* bn_m = (const float*)d_in[6];
    const float* bn_v = (const float*)d_in[7];
    float* out = (float*)d_out;

    char* ws = (char*)d_ws;
    short* Wb  = (short*)ws;                    // 12288 bf16
    short* PAb = (short*)(ws + 24576);          //  3072 bf16
    float* scl = (float*)(ws + 30720);          //    64 f32
    float* sft = (float*)(ws + 30976);          //    64 f32

    stgcn_prep<<<61, 256, 0, stream>>>(Wc, PA, bn_g, bn_b, bn_m, bn_v, Wb, PAb, scl, sft);
    stgcn_main<<<N_ * NT_BLK, 256, 0, stream>>>(x, cb, Wb, PAb, scl, sft, out);
}